// Round 1
// baseline (1572.436 us; speedup 1.0000x reference)
//
#include <hip/hip_runtime.h>
#include <hip/hip_bf16.h>
#include <float.h>

#define BATCH 4096
#define NLEAF 50000
#define DIM   256
#define NSPLIT 16
#define LPS   (NLEAF / NSPLIT)      /* 3125 */
#define BM 128
#define BN 128
#define KB 32
#define MBLK (BATCH / BM)           /* 32 */
#define NTILE ((LPS + BN - 1) / BN) /* 25 */

// Sorted ascending 5-element insertion, all indices compile-time static.
__device__ __forceinline__ void insert5(float key, int id, float (&k)[5], int (&ix)[5]) {
    if (key < k[4]) {
        if (key < k[3]) {
            k[4] = k[3]; ix[4] = ix[3];
            if (key < k[2]) {
                k[3] = k[2]; ix[3] = ix[2];
                if (key < k[1]) {
                    k[2] = k[1]; ix[2] = ix[1];
                    if (key < k[0]) {
                        k[1] = k[0]; ix[1] = ix[0];
                        k[0] = key;  ix[0] = id;
                    } else { k[1] = key; ix[1] = id; }
                } else { k[2] = key; ix[2] = id; }
            } else { k[3] = key; ix[3] = id; }
        } else { k[4] = key; ix[4] = id; }
    }
}

// Kernel 0: row norms + precomputed distance factors.
// afac[m] = 2/(1-|x|^2), bfac[l] = 1/(1-|y|^2)
__global__ void norms_k(const float* __restrict__ z, const float* __restrict__ leaf,
                        float* __restrict__ x2, float* __restrict__ afac,
                        float* __restrict__ y2, float* __restrict__ bfac) {
    int w = (blockIdx.x * 256 + threadIdx.x) >> 6;   // one wave per row
    int lane = threadIdx.x & 63;
    if (w >= BATCH + NLEAF) return;
    const float* row = (w < BATCH) ? (z + (size_t)w * DIM)
                                   : (leaf + (size_t)(w - BATCH) * DIM);
    float4 v = reinterpret_cast<const float4*>(row)[lane];
    float s = v.x * v.x + v.y * v.y + v.z * v.z + v.w * v.w;
#pragma unroll
    for (int off = 32; off > 0; off >>= 1) s += __shfl_down(s, off, 64);
    if (lane == 0) {
        if (w < BATCH) { x2[w] = s; afac[w] = 2.0f / (1.0f - s); }
        else { int l = w - BATCH; y2[l] = s; bfac[l] = 1.0f / (1.0f - s); }
    }
}

// Kernel 1: fused fp32 GEMM + per-row top-5 over this block's leaf split.
// key = max(x2 + y2 - 2*xy, 0) * bfac  (monotone in distance per row)
__global__ __launch_bounds__(256, 1) void dist_topk_k(
        const float* __restrict__ z, const float* __restrict__ leaf,
        const float* __restrict__ x2, const float* __restrict__ y2,
        const float* __restrict__ bfac,
        float* __restrict__ partK, int* __restrict__ partI) {
    __shared__ float smem[10368];                          // 41472 B
    float (*As)[BM + 4] = reinterpret_cast<float (*)[BM + 4]>(smem);
    float (*Bs)[BN + 4] = reinterpret_cast<float (*)[BN + 4]>(smem + KB * (BM + 4));
    float* xt = smem + 2 * KB * (BM + 4);   // [BM]
    float* yt = xt + BM;                    // [BN]
    float* bt = yt + BN;                    // [BN]

    const int t  = threadIdx.x;
    const int tx = t & 15;
    const int ty = t >> 4;
    const int m0 = blockIdx.x * BM;
    const int split = blockIdx.y;
    const int lbase = split * LPS;
    const int lend  = lbase + LPS;

    float t5k[8][5]; int t5i[8][5];
#pragma unroll
    for (int i = 0; i < 8; ++i) {
#pragma unroll
        for (int q = 0; q < 5; ++q) { t5k[i][q] = FLT_MAX; t5i[i][q] = 0; }
    }

    if (t < BM) xt[t] = x2[m0 + t];

    for (int nt = 0; nt < NTILE; ++nt) {
        const int l0 = lbase + nt * BN;
        __syncthreads();                    // prev epilogue done before yt/bt overwrite
        if (t < BN) {
            int gl = l0 + t;
            bool valid = gl < lend;
            yt[t] = valid ? y2[gl]   : 1e30f;
            bt[t] = valid ? bfac[gl] : 1.0f;
        }

        float acc[8][8];
#pragma unroll
        for (int i = 0; i < 8; ++i)
#pragma unroll
            for (int j = 0; j < 8; ++j) acc[i][j] = 0.0f;

        for (int kc = 0; kc < DIM / KB; ++kc) {
            const int k0 = kc * KB;
            __syncthreads();                // prev compute done before LDS overwrite
#pragma unroll
            for (int i = 0; i < 4; ++i) {
                int idx = t + 256 * i;      // 1024 float4 per tile-chunk
                int row = idx >> 3, kg = idx & 7;
                float4 va = reinterpret_cast<const float4*>(z + (size_t)(m0 + row) * DIM + k0)[kg];
                As[kg * 4 + 0][row] = va.x; As[kg * 4 + 1][row] = va.y;
                As[kg * 4 + 2][row] = va.z; As[kg * 4 + 3][row] = va.w;
                int gl = l0 + row; if (gl > NLEAF - 1) gl = NLEAF - 1;   // clamp for mem safety
                float4 vb = reinterpret_cast<const float4*>(leaf + (size_t)gl * DIM + k0)[kg];
                Bs[kg * 4 + 0][row] = vb.x; Bs[kg * 4 + 1][row] = vb.y;
                Bs[kg * 4 + 2][row] = vb.z; Bs[kg * 4 + 3][row] = vb.w;
            }
            __syncthreads();
#pragma unroll 4
            for (int kk = 0; kk < KB; ++kk) {
                const float4 a0 = *reinterpret_cast<const float4*>(&As[kk][ty * 8]);
                const float4 a1 = *reinterpret_cast<const float4*>(&As[kk][ty * 8 + 4]);
                const float4 b0 = *reinterpret_cast<const float4*>(&Bs[kk][tx * 4]);
                const float4 b1 = *reinterpret_cast<const float4*>(&Bs[kk][64 + tx * 4]);
                float av[8] = {a0.x, a0.y, a0.z, a0.w, a1.x, a1.y, a1.z, a1.w};
                float bv[8] = {b0.x, b0.y, b0.z, b0.w, b1.x, b1.y, b1.z, b1.w};
#pragma unroll
                for (int i = 0; i < 8; ++i)
#pragma unroll
                    for (int j = 0; j < 8; ++j)
                        acc[i][j] = fmaf(av[i], bv[j], acc[i][j]);
            }
        }

        // epilogue: fold this tile into running per-row top-5
        float xv[8];
#pragma unroll
        for (int i = 0; i < 8; ++i) xv[i] = xt[ty * 8 + i];
#pragma unroll
        for (int j = 0; j < 8; ++j) {
            int nn = (j < 4) ? (tx * 4 + j) : (64 + tx * 4 + (j - 4));
            float yv = yt[nn], bv = bt[nn];
            int gid = l0 + nn;
#pragma unroll
            for (int i = 0; i < 8; ++i) {
                float sq = fmaxf(xv[i] + yv - 2.0f * acc[i][j], 0.0f);
                insert5(sq * bv, gid, t5k[i], t5i[i]);
            }
        }
    }

    // Block-level merge: 16 threads x 5 candidates per row -> top-5 per row.
    float* mk = smem;                                   // [64][81]
    int*   mi = reinterpret_cast<int*>(smem + 5184);    // [64][81]
    for (int ph = 0; ph < 2; ++ph) {                    // rows 0..63 then 64..127
        __syncthreads();
        if ((ty >> 3) == ph) {
            int rbase = (ty & 7) * 8;
#pragma unroll
            for (int i = 0; i < 8; ++i) {
                int r = rbase + i;
#pragma unroll
                for (int q = 0; q < 5; ++q) {
                    mk[r * 81 + tx * 5 + q] = t5k[i][q];
                    mi[r * 81 + tx * 5 + q] = t5i[i][q];
                }
            }
        }
        __syncthreads();
        if (t < 64) {
            float fk[5]; int fi[5];
#pragma unroll
            for (int q = 0; q < 5; ++q) { fk[q] = FLT_MAX; fi[q] = 0; }
            for (int q = 0; q < 80; ++q)
                insert5(mk[t * 81 + q], mi[t * 81 + q], fk, fi);
            int grow = m0 + ph * 64 + t;
            size_t base = ((size_t)grow * NSPLIT + split) * 5;
#pragma unroll
            for (int q = 0; q < 5; ++q) { partK[base + q] = fk[q]; partI[base + q] = fi[q]; }
        }
    }
}

// Kernel 2: merge NSPLIT partials per row, compute acosh once, write outputs.
__global__ void finalize_k(const float* __restrict__ partK, const int* __restrict__ partI,
                           const float* __restrict__ afac, const int* __restrict__ ids,
                           const float* __restrict__ thr, float* __restrict__ out) {
    int row = blockIdx.x * 256 + threadIdx.x;
    if (row >= BATCH) return;
    float fk[5]; int fi[5];
#pragma unroll
    for (int q = 0; q < 5; ++q) { fk[q] = FLT_MAX; fi[q] = 0; }
    size_t base = (size_t)row * NSPLIT * 5;
    for (int s = 0; s < NSPLIT * 5; ++s) insert5(partK[base + s], partI[base + s], fk, fi);
    float a = afac[row];
    float u = fk[0] * a;              // u = 2*sq/((1-x2)(1-y2)); arg = 1+u
    u = fmaxf(u, 1e-7f);              // matches reference arg >= 1+EPS clamp
    float d = log1pf(u + sqrtf(u * (u + 2.0f)));   // acosh(1+u)
    out[row] = d;                                  // scores
    out[BATCH + row] = (d > thr[0]) ? 1.0f : 0.0f; // is_ood
#pragma unroll
    for (int q = 0; q < 5; ++q)
        out[2 * BATCH + (size_t)row * 5 + q] = (float)ids[fi[q]];  // topk ids
}

extern "C" void kernel_launch(void* const* d_in, const int* in_sizes, int n_in,
                              void* d_out, int out_size, void* d_ws, size_t ws_size,
                              hipStream_t stream) {
    const float* z    = (const float*)d_in[0];
    const float* leaf = (const float*)d_in[1];
    const int*   ids  = (const int*)d_in[2];
    const float* thr  = (const float*)d_in[3];
    float* out = (float*)d_out;

    float* wsf   = (float*)d_ws;
    float* x2    = wsf;                 // 4096
    float* afac  = wsf + 4096;          // 4096
    float* y2    = wsf + 8192;          // 50000
    float* bfac  = wsf + 58192;         // 50000
    float* partK = wsf + 108192;        // 4096*16*5 = 327680
    int*   partI = (int*)(wsf + 108192 + BATCH * NSPLIT * 5);

    norms_k<<<(BATCH + NLEAF) / 4, 256, 0, stream>>>(z, leaf, x2, afac, y2, bfac);
    dist_topk_k<<<dim3(MBLK, NSPLIT), 256, 0, stream>>>(z, leaf, x2, y2, bfac, partK, partI);
    finalize_k<<<BATCH / 256, 256, 0, stream>>>(partK, partI, afac, ids, thr, out);
}

// Round 2
// 680.120 us; speedup vs baseline: 2.3120x; 2.3120x over previous
//
#include <hip/hip_runtime.h>
#include <hip/hip_bf16.h>
#include <float.h>
#include <stdint.h>

#define BATCH 4096
#define NLEAF 50000
#define DIM   256
#define NTILES 391                 /* ceil(50000/128) */
#define NGRP  (NTILES * 8)         /* 3128 16-leaf groups (incl. pad groups) */
#define MAXC  20                   /* candidate-group cap per row */

typedef short s8v __attribute__((ext_vector_type(8)));   // 8 bf16 bits
typedef float f4  __attribute__((ext_vector_type(4)));

// ---------- helpers ----------
__device__ __forceinline__ unsigned short bf16_rne(float f) {
    uint32_t u = __float_as_uint(f);
    uint32_t r = (u + 0x7FFFu + ((u >> 16) & 1u)) >> 16;
    return (unsigned short)r;
}

__device__ __forceinline__ void insert5v(float key, float (&k)[5]) {
    if (key < k[4]) {
        if (key < k[3]) { k[4]=k[3];
            if (key < k[2]) { k[3]=k[2];
                if (key < k[1]) { k[2]=k[1];
                    if (key < k[0]) { k[1]=k[0]; k[0]=key; } else k[1]=key;
                } else k[2]=key;
            } else k[3]=key;
        } else k[4]=key;
    }
}

__device__ __forceinline__ bool lexless(float k, int i, float K, int I) {
    return (k < K) || (k == K && i < I);
}
__device__ __forceinline__ void insert5lex(float key, int id, float (&k)[5], int (&ix)[5]) {
    if (lexless(key, id, k[4], ix[4])) {
        if (lexless(key, id, k[3], ix[3])) { k[4]=k[3]; ix[4]=ix[3];
            if (lexless(key, id, k[2], ix[2])) { k[3]=k[2]; ix[3]=ix[2];
                if (lexless(key, id, k[1], ix[1])) { k[2]=k[1]; ix[2]=ix[1];
                    if (lexless(key, id, k[0], ix[0])) { k[1]=k[0]; ix[1]=ix[0]; k[0]=key; ix[0]=id; }
                    else { k[1]=key; ix[1]=id; }
                } else { k[2]=key; ix[2]=id; }
            } else { k[3]=key; ix[3]=id; }
        } else { k[4]=key; ix[4]=id; }
    }
}

__device__ __forceinline__ void gload_lds16(const void* g, void* l) {
    __builtin_amdgcn_global_load_lds(
        (const __attribute__((address_space(1))) uint32_t*)g,
        (__attribute__((address_space(3))) uint32_t*)l, 16, 0, 0);
}

// ---------- kernel 0: norms ----------
__global__ void norms_k(const float* __restrict__ z, const float* __restrict__ leaf,
                        float* __restrict__ x2, float* __restrict__ afac,
                        float* __restrict__ y2, float* __restrict__ bfac) {
    int w = (blockIdx.x * 256 + threadIdx.x) >> 6;
    int lane = threadIdx.x & 63;
    if (w >= BATCH + NLEAF) return;
    const float* row = (w < BATCH) ? (z + (size_t)w * DIM) : (leaf + (size_t)(w - BATCH) * DIM);
    float4 v = reinterpret_cast<const float4*>(row)[lane];
    float s = v.x*v.x + v.y*v.y + v.z*v.z + v.w*v.w;
#pragma unroll
    for (int off = 32; off > 0; off >>= 1) s += __shfl_down(s, off, 64);
    if (lane == 0) {
        if (w < BATCH) { x2[w] = s; afac[w] = 2.0f / (1.0f - s); }
        else { int l = w - BATCH; y2[l] = s; bfac[l] = 1.0f / (1.0f - s); }
    }
}

// ---------- kernel 1: fp32 -> bf16 hi/lo ----------
__global__ void cvt_k(const float* __restrict__ z, const float* __restrict__ leaf,
                      unsigned short* __restrict__ zh, unsigned short* __restrict__ zl,
                      unsigned short* __restrict__ lh, unsigned short* __restrict__ ll) {
    int idx = blockIdx.x * 256 + threadIdx.x;          // one float4 per thread
    const int ZQ = BATCH * (DIM / 4);                  // 262144
    const int TQ = (BATCH + NLEAF) * (DIM / 4);
    if (idx >= TQ) return;
    const float* src; unsigned short *dh, *dl; size_t o;
    if (idx < ZQ) { src = z;    o = (size_t)idx * 4;            dh = zh; dl = zl; }
    else          { src = leaf; o = (size_t)(idx - ZQ) * 4;     dh = lh; dl = ll; src = leaf; }
    float4 v = *reinterpret_cast<const float4*>(src + o);
    ushort4 h, l;
    float f[4] = {v.x, v.y, v.z, v.w};
    unsigned short hh[4], llo[4];
#pragma unroll
    for (int i = 0; i < 4; ++i) {
        hh[i] = bf16_rne(f[i]);
        float fh = __uint_as_float(((uint32_t)hh[i]) << 16);
        llo[i] = bf16_rne(f[i] - fh);
    }
    h.x=hh[0]; h.y=hh[1]; h.z=hh[2]; h.w=hh[3];
    l.x=llo[0]; l.y=llo[1]; l.z=llo[2]; l.w=llo[3];
    *reinterpret_cast<ushort4*>(dh + o) = h;
    *reinterpret_cast<ushort4*>(dl + o) = l;
}

// ---------- kernel 2: MFMA 3-pass GEMM + per-16-leaf-group min ----------
// grid: (32 M-tiles, 391 N-tiles), 256 threads. LDS: 4 x [128][64] bf16 tiles
// (Ah,Al,Bh,Bl) + yt/bt/xt. Swizzle: 16B slot s -> s ^ (row&7), applied on the
// global SOURCE of global_load_lds (LDS linear) and on ds_read addresses.
__global__ __launch_bounds__(256, 2) void gemm_min_k(
        const unsigned short* __restrict__ zh, const unsigned short* __restrict__ zl,
        const unsigned short* __restrict__ lh, const unsigned short* __restrict__ ll,
        const float* __restrict__ x2, const float* __restrict__ y2,
        const float* __restrict__ bfac, float* __restrict__ mins) {
    extern __shared__ char sm[];
    float* yt = (float*)(sm + 65536);
    float* bt = (float*)(sm + 66048);
    float* xt = (float*)(sm + 66560);

    const int t = threadIdx.x;
    const int w = t >> 6, l = t & 63;
    const int wr = w >> 1, wc = w & 1;
    const int lr = l & 15, lg = l >> 4;
    const int m0 = blockIdx.x * 128;
    const int ntile = blockIdx.y;
    const int l0 = ntile * 128;

    if (t < 128) {
        xt[t] = x2[m0 + t];
        int gl = l0 + t;
        bool v = gl < NLEAF;
        yt[t] = v ? y2[gl] : 1e30f;
        bt[t] = v ? bfac[gl] : 1.0f;
    }

    // per-thread staging source offsets (bytes within hi/lo arrays), j-unrolled
    int soff[16];
#pragma unroll
    for (int j = 0; j < 16; ++j) {
        int cc = (4 * j + w) & 15;
        int r  = cc * 8 + (l >> 3);
        int sl = (l & 7) ^ (r & 7);
        int grow = (j < 8) ? (m0 + r) : ((l0 + r < NLEAF) ? (l0 + r) : (NLEAF - 1));
        soff[j] = grow * 512 + sl * 16;
    }

    f4 acc[4][4];
#pragma unroll
    for (int i = 0; i < 4; ++i)
#pragma unroll
        for (int j = 0; j < 4; ++j) acc[i][j] = (f4){0.f, 0.f, 0.f, 0.f};

    // frag ds_read base offsets (bytes, incl. row-swizzle component)
    int aoffs[4], boffs[4];
#pragma unroll
    for (int f = 0; f < 4; ++f) {
        int ra = wr * 64 + f * 16 + lr;
        aoffs[f] = ra * 128 + ((ra & 7) << 4);
        int rb = wc * 64 + f * 16 + lr;
        boffs[f] = rb * 128 + ((rb & 7) << 4);
    }
    const int sx = lg << 4;

    for (int ks = 0; ks < 4; ++ks) {
        __syncthreads();                       // prior compute done, LDS reusable
        const int kb = ks * 128;               // byte offset along K (64 bf16)
#pragma unroll
        for (int j = 0; j < 16; ++j) {
            const char* base = (j < 4) ? (const char*)zh
                             : (j < 8) ? (const char*)zl
                             : (j < 12) ? (const char*)lh
                             : (const char*)ll;
            gload_lds16(base + soff[j] + kb, sm + (4 * j + w) * 1024);
        }
        __syncthreads();                       // drains vmcnt: tiles ready
#pragma unroll
        for (int kk = 0; kk < 2; ++kk) {
            const int x = sx ^ (kk << 6);
            s8v ah[4], al[4], bh[4], bl[4];
#pragma unroll
            for (int f = 0; f < 4; ++f) {
                ah[f] = *(const s8v*)(sm +         (aoffs[f] ^ x));
                al[f] = *(const s8v*)(sm + 16384 + (aoffs[f] ^ x));
                bh[f] = *(const s8v*)(sm + 32768 + (boffs[f] ^ x));
                bl[f] = *(const s8v*)(sm + 49152 + (boffs[f] ^ x));
            }
#pragma unroll
            for (int fi = 0; fi < 4; ++fi)
#pragma unroll
                for (int fj = 0; fj < 4; ++fj) {
                    acc[fi][fj] = __builtin_amdgcn_mfma_f32_16x16x32_bf16(ah[fi], bh[fj], acc[fi][fj], 0, 0, 0);
                    acc[fi][fj] = __builtin_amdgcn_mfma_f32_16x16x32_bf16(ah[fi], bl[fj], acc[fi][fj], 0, 0, 0);
                    acc[fi][fj] = __builtin_amdgcn_mfma_f32_16x16x32_bf16(al[fi], bh[fj], acc[fi][fj], 0, 0, 0);
                }
        }
    }

    // epilogue: key = (x2 + y2 - 2*dot) * bfac ; min over each 16-leaf group
    float xv[4][4];
#pragma unroll
    for (int fi = 0; fi < 4; ++fi) {
        float4 xq = *(const float4*)&xt[wr * 64 + fi * 16 + lg * 4];
        xv[fi][0]=xq.x; xv[fi][1]=xq.y; xv[fi][2]=xq.z; xv[fi][3]=xq.w;
    }
    float bv[4], c1[4];
#pragma unroll
    for (int fj = 0; fj < 4; ++fj) {
        int nn = wc * 64 + fj * 16 + lr;   // lr only offsets within group; y/b per-n
        float y = yt[nn]; float b = bt[nn];
        bv[fj] = b; c1[fj] = y * b;
    }
    const int a1 = ((l ^ 1) << 2), a2 = ((l ^ 2) << 2), a4 = ((l ^ 4) << 2), a8 = ((l ^ 8) << 2);
#pragma unroll
    for (int fi = 0; fi < 4; ++fi)
#pragma unroll
        for (int fj = 0; fj < 4; ++fj) {
            const float m2b = -2.0f * bv[fj];
#pragma unroll
            for (int reg = 0; reg < 4; ++reg) {
                float a = acc[fi][fj][reg];
                float key = fmaf(a, m2b, fmaf(xv[fi][reg], bv[fj], c1[fj]));
                key = fminf(key, __int_as_float(__builtin_amdgcn_ds_bpermute(a1, __float_as_int(key))));
                key = fminf(key, __int_as_float(__builtin_amdgcn_ds_bpermute(a2, __float_as_int(key))));
                key = fminf(key, __int_as_float(__builtin_amdgcn_ds_bpermute(a4, __float_as_int(key))));
                key = fminf(key, __int_as_float(__builtin_amdgcn_ds_bpermute(a8, __float_as_int(key))));
                if (lr == 0) {
                    int row = m0 + wr * 64 + fi * 16 + lg * 4 + reg;
                    int g = ntile * 8 + wc * 4 + fj;
                    mins[(size_t)row * NGRP + g] = key;
                }
            }
        }
}

// ---------- kernel 3: per-row 5th-smallest group-min + candidate collection ----------
__global__ void select_k(const float* __restrict__ mins, int* __restrict__ cnt,
                         int* __restrict__ cand) {
    int w = threadIdx.x >> 6, l = threadIdx.x & 63;
    int row = blockIdx.x * 4 + w;
    const float* mrow = mins + (size_t)row * NGRP;
    float t5[5] = {FLT_MAX, FLT_MAX, FLT_MAX, FLT_MAX, FLT_MAX};
    for (int j = 0; j < 49; ++j) {
        int g = j * 64 + l;
        float m = (g < NGRP) ? mrow[g] : FLT_MAX;
        insert5v(m, t5);
    }
    // merge sorted-5 lists across 64 lanes (xor butterfly)
#pragma unroll
    for (int s = 1; s < 64; s <<= 1) {
        float o[5];
#pragma unroll
        for (int q = 0; q < 5; ++q) o[q] = __shfl_xor(t5[q], s, 64);
        float n0 = fminf(t5[0], o[0]);
        float n1 = fminf(fminf(t5[1], o[1]), fmaxf(t5[0], o[0]));
        float n2 = fminf(fminf(t5[2], o[2]), fminf(fmaxf(t5[0], o[1]), fmaxf(t5[1], o[0])));
        float n3 = fminf(fminf(t5[3], o[3]),
                   fminf(fmaxf(t5[0], o[2]), fminf(fmaxf(t5[1], o[1]), fmaxf(t5[2], o[0]))));
        float n4 = fminf(fminf(t5[4], o[4]),
                   fminf(fminf(fmaxf(t5[0], o[3]), fmaxf(t5[1], o[2])),
                         fminf(fmaxf(t5[2], o[1]), fmaxf(t5[3], o[0]))));
        t5[0]=n0; t5[1]=n1; t5[2]=n2; t5[3]=n3; t5[4]=n4;
    }
    float thr = t5[4];
    thr += fmaxf(2e-3f * fabsf(thr), 2e-4f);    // margin >> hi/lo-split error
    int base = 0;
    int* crow = cand + row * MAXC;
    for (int j = 0; j < 49; ++j) {
        int g = j * 64 + l;
        bool p = (g < NGRP) && (mrow[g] <= thr);
        unsigned long long b = __ballot(p);
        int off = __popcll(b & ((1ull << l) - 1ull));
        if (p && base + off < MAXC) crow[base + off] = g;
        base += (int)__popcll(b);
    }
    if (l == 0) cnt[row] = base < MAXC ? base : MAXC;
}

// ---------- kernel 4: exact fp32 recheck of candidate groups + outputs ----------
__global__ __launch_bounds__(256) void recheck_k(
        const float* __restrict__ z, const float* __restrict__ leaf,
        const float* __restrict__ x2, const float* __restrict__ y2,
        const float* __restrict__ bfac, const float* __restrict__ afac,
        const int* __restrict__ cnt, const int* __restrict__ cand,
        const int* __restrict__ ids, const float* __restrict__ thr,
        float* __restrict__ out) {
    __shared__ float mk[20];
    __shared__ int   mi[20];
    const int row = blockIdx.x;
    const int t = threadIdx.x, w = t >> 6, l = t & 63;
    float4 zr = *(const float4*)(z + (size_t)row * DIM + l * 4);
    const float x2r = x2[row];
    const int nc = cnt[row];
    float k5[5]; int i5[5];
#pragma unroll
    for (int q = 0; q < 5; ++q) { k5[q] = FLT_MAX; i5[q] = 0x7FFFFFFF; }
    for (int ci = w; ci < nc; ci += 4) {
        int g = cand[row * MAXC + ci];
#pragma unroll 1
        for (int jj = 0; jj < 16; ++jj) {
            int id = g * 16 + jj;
            if (id >= NLEAF) break;
            float4 lf = *(const float4*)(leaf + (size_t)id * DIM + l * 4);
            float d = zr.x * lf.x;
            d = fmaf(zr.y, lf.y, d); d = fmaf(zr.z, lf.z, d); d = fmaf(zr.w, lf.w, d);
#pragma unroll
            for (int s = 1; s < 64; s <<= 1) d += __shfl_xor(d, s, 64);
            float sq = fmaxf(x2r + y2[id] - 2.0f * d, 0.0f);
            float key = sq * bfac[id];
            insert5lex(key, id, k5, i5);
        }
    }
    if (l == 0) {
#pragma unroll
        for (int q = 0; q < 5; ++q) { mk[w * 5 + q] = k5[q]; mi[w * 5 + q] = i5[q]; }
    }
    __syncthreads();
    if (t == 0) {
        float fk[5]; int fi[5];
#pragma unroll
        for (int q = 0; q < 5; ++q) { fk[q] = FLT_MAX; fi[q] = 0x7FFFFFFF; }
        for (int s = 0; s < 20; ++s) insert5lex(mk[s], mi[s], fk, fi);
        float u = fk[0] * afac[row];
        u = fmaxf(u, 1e-7f);
        float dd = log1pf(u + sqrtf(u * (u + 2.0f)));
        out[row] = dd;
        out[BATCH + row] = (dd > thr[0]) ? 1.0f : 0.0f;
#pragma unroll
        for (int q = 0; q < 5; ++q)
            out[2 * BATCH + (size_t)row * 5 + q] = (float)ids[fi[q]];
    }
}

extern "C" void kernel_launch(void* const* d_in, const int* in_sizes, int n_in,
                              void* d_out, int out_size, void* d_ws, size_t ws_size,
                              hipStream_t stream) {
    const float* z    = (const float*)d_in[0];
    const float* leaf = (const float*)d_in[1];
    const int*   ids  = (const int*)d_in[2];
    const float* thr  = (const float*)d_in[3];
    float* out = (float*)d_out;

    char* ws = (char*)d_ws;
    float* x2   = (float*)(ws + 0);                 // 16384 B
    float* afac = (float*)(ws + 16384);             // 16384 B
    float* y2   = (float*)(ws + 32768);             // 200000 B
    float* bfac = (float*)(ws + 232768);            // 200000 B
    unsigned short* zh = (unsigned short*)(ws + 432768);     // 2 MB
    unsigned short* zl = (unsigned short*)(ws + 2529920);    // 2 MB
    unsigned short* lh = (unsigned short*)(ws + 4627072);    // 25.6 MB
    unsigned short* ll = (unsigned short*)(ws + 30227072);   // 25.6 MB
    float* mins = (float*)(ws + 55827072);          // 4096*3128*4 = 51.25 MB
    int* cnt  = (int*)(ws + 107076224);             // 16 KB
    int* cand = (int*)(ws + 107092608);             // 4096*20*4

    norms_k<<<(BATCH + NLEAF) / 4, 256, 0, stream>>>(z, leaf, x2, afac, y2, bfac);
    {
        int tq = (BATCH + NLEAF) * (DIM / 4);
        cvt_k<<<(tq + 255) / 256, 256, 0, stream>>>(z, leaf, zh, zl, lh, ll);
    }
    gemm_min_k<<<dim3(32, NTILES), 256, 67072, stream>>>(zh, zl, lh, ll, x2, y2, bfac, mins);
    select_k<<<BATCH / 4, 256, 0, stream>>>(mins, cnt, cand);
    recheck_k<<<BATCH, 256, 0, stream>>>(z, leaf, x2, y2, bfac, afac, cnt, cand, ids, thr, out);
}